// Round 4
// baseline (849.030 us; speedup 1.0000x reference)
//
#include <hip/hip_runtime.h>
#include <stdint.h>
#include <stddef.h>

#define DIN    512
#define BGR    1024
#define NGATE  2048   // 4*DIN
#define KQ     1024   // 2*DIN (q_star width)
#define DOUT   512
#define TSTEPS 6

typedef unsigned short ushort_t;
typedef short bf16x8 __attribute__((ext_vector_type(8)));
typedef unsigned short u16x8 __attribute__((ext_vector_type(8)));
typedef float f32x4 __attribute__((ext_vector_type(4)));

__device__ __forceinline__ float b2f(unsigned short u) {
    unsigned int i = ((unsigned int)u) << 16;
    float f;
    __builtin_memcpy(&f, &i, 4);
    return f;
}

__device__ __forceinline__ unsigned short f2b(float f) {
    unsigned int i;
    __builtin_memcpy(&i, &f, 4);
    unsigned int lsb = (i >> 16) & 1u;
    i += 0x7fffu + lsb;   // round-to-nearest-even
    return (unsigned short)(i >> 16);
}

__device__ __forceinline__ float fast_sigmoid(float v) {
    return 1.f / (1.f + __expf(-v));
}

__device__ __forceinline__ float fast_tanh(float v) {
    float t = fabsf(v);
    float e = __expf(-2.f * t);
    float r = (1.f - e) / (1.f + e);
    return v < 0.f ? -r : r;
}

// ---------------------------------------------------------------------------
// Dtype probe: flags[t]=1 if tensor t is f32, 0 if bf16.
// bf16 tensor: even-index u16s are bf16 values -> exponent field sane (~100%).
// f32 tensor:  even-index u16s are low mantissa bits -> exponent ~uniform (~19%).
// Tensors: 0=x 1=Wih 2=Whh 3=bih 4=bhh 5=Wpost 6=bpost
// ---------------------------------------------------------------------------
__global__ void probe_dtypes(const ushort_t* x, const ushort_t* Wih,
                             const ushort_t* Whh, const ushort_t* bih,
                             const ushort_t* bhh, const ushort_t* Wpost,
                             const ushort_t* bpost, int* flags)
{
    __shared__ int cnt[7];
    const int tid = threadIdx.x;
    if (tid < 7) cnt[tid] = 0;
    __syncthreads();
    const int t = tid >> 5;   // 32 threads per tensor
    const int l = tid & 31;
    if (t < 7) {
        const ushort_t* p = (t == 0) ? x : (t == 1) ? Wih : (t == 2) ? Whh
                          : (t == 3) ? bih : (t == 4) ? bhh
                          : (t == 5) ? Wpost : bpost;
        int good = 0;
        for (int i = 0; i < 4; i++) {
            ushort_t u = p[(l * 4 + i) * 2];   // even indices 0..254 (min len 512)
            int ex = (u >> 7) & 0xFF;
            if (ex == 0 || (ex >= 96 && ex <= 143)) good++;  // zero or |v| in ~[2^-31,2^16]
        }
        atomicAdd(&cnt[t], good);
    }
    __syncthreads();
    if (tid < 7) flags[tid] = (cnt[tid] < 96) ? 1 : 0;   // <75% sane -> f32
}

// ---------------------------------------------------------------------------
// GEMM: C[m][n] = sum_k A[m][k]*B[n][k] (+bias[n]); A,B bf16 row-major
// (internally produced). MODE 0: C f32 store (z).
// MODE 1: C f32 relu store (final out — reference output dtype is float32).
// BM=128, BN=64, BK=32; 256 threads = 4 waves (2x2), wave computes 64x32.
// ---------------------------------------------------------------------------
#define BM 128
#define BN 64
#define BK 32

template <int MODE>
__global__ __launch_bounds__(256)
void gemm_bt(const ushort_t* __restrict__ Ag, const ushort_t* __restrict__ Bg,
             const float* __restrict__ bias, float* __restrict__ Cout,
             int M, int N, int K)
{
    __shared__ __align__(16) ushort_t As[BM * BK];
    __shared__ __align__(16) ushort_t Bs[BN * BK];

    const int tid  = threadIdx.x;
    const int lane = tid & 63;
    const int w    = tid >> 6;
    const int wr   = w >> 1;
    const int wc   = w & 1;
    const int lrow = lane & 15;
    const int quad = lane >> 4;

    const int n0 = blockIdx.x * BN;
    const int m0 = blockIdx.y * BM;

    const int srow = tid >> 2;        // 0..63
    const int scol = (tid & 3) * 8;   // 0,8,16,24

    f32x4 acc[4][2];
#pragma unroll
    for (int i = 0; i < 4; i++)
#pragma unroll
        for (int j = 0; j < 2; j++)
            acc[i][j] = (f32x4){0.f, 0.f, 0.f, 0.f};

    for (int kt = 0; kt < K; kt += BK) {
        bf16x8 a0v = *(const bf16x8*)(Ag + ((size_t)(m0 + srow) * K + kt + scol));
        bf16x8 a1v = *(const bf16x8*)(Ag + ((size_t)(m0 + 64 + srow) * K + kt + scol));
        bf16x8 bv  = *(const bf16x8*)(Bg + ((size_t)(n0 + srow) * K + kt + scol));
        __syncthreads();
        *(bf16x8*)&As[srow * BK + scol]        = a0v;
        *(bf16x8*)&As[(64 + srow) * BK + scol] = a1v;
        *(bf16x8*)&Bs[srow * BK + scol]        = bv;
        __syncthreads();

        bf16x8 af[4], bfr[2];
#pragma unroll
        for (int mi = 0; mi < 4; mi++)
            af[mi] = *(const bf16x8*)&As[(wr * 64 + mi * 16 + lrow) * BK + quad * 8];
#pragma unroll
        for (int ni = 0; ni < 2; ni++)
            bfr[ni] = *(const bf16x8*)&Bs[(wc * 32 + ni * 16 + lrow) * BK + quad * 8];

#pragma unroll
        for (int mi = 0; mi < 4; mi++)
#pragma unroll
            for (int ni = 0; ni < 2; ni++)
                acc[mi][ni] = __builtin_amdgcn_mfma_f32_16x16x32_bf16(
                    af[mi], bfr[ni], acc[mi][ni], 0, 0, 0);
    }

    // D layout: row = quad*4 + reg, col = lane&15   [m89/m91]
#pragma unroll
    for (int mi = 0; mi < 4; mi++) {
#pragma unroll
        for (int ni = 0; ni < 2; ni++) {
#pragma unroll
            for (int r = 0; r < 4; r++) {
                int gm = m0 + wr * 64 + mi * 16 + quad * 4 + r;
                int gn = n0 + wc * 32 + ni * 16 + lrow;
                float v = acc[mi][ni][r] + bias[gn];
                if (MODE == 1) {
                    // NaN-transparent relu (NaN preserved as diagnostic)
                    if (!(v > 0.f) && (v == v)) v = 0.f;
                }
                Cout[(size_t)gm * N + gn] = v;
            }
        }
    }
}

// ---------------------------------------------------------------------------
// Fused LSTM cell (row b) + segment softmax attention (graph b).
// One block (256 thr) per graph; batch sorted -> CSR offsets, no atomics.
// x read path switches on flags[0] (f32 vs bf16).
// ---------------------------------------------------------------------------
__global__ __launch_bounds__(256)
void attn_step(const ushort_t* __restrict__ x, const int* __restrict__ offs,
               const float* __restrict__ z, float* __restrict__ c,
               ushort_t* __restrict__ A, float* __restrict__ ebuf,
               const int* __restrict__ flags)
{
    const int b    = blockIdx.x;
    const int tid  = threadIdx.x;
    const int lane = tid & 63;
    const int w    = tid >> 6;
    const int xf32 = flags[0];

    __shared__ float qsh[DIN];
    __shared__ float smax[4];
    __shared__ float ssum[4];

    // ---- phase 0: LSTM cell for graph-row b (gate order i,f,g,o) ----
    const float* zrow = z + (size_t)b * NGATE;
    for (int d = tid; d < DIN; d += 256) {
        float zi = zrow[d];
        float zf = zrow[DIN + d];
        float zg = zrow[2 * DIN + d];
        float zo = zrow[3 * DIN + d];
        float cc = c[(size_t)b * DIN + d];
        cc = fast_sigmoid(zf) * cc + fast_sigmoid(zi) * fast_tanh(zg);
        float hh = fast_sigmoid(zo) * fast_tanh(cc);
        c[(size_t)b * DIN + d] = cc;
        A[(size_t)b * KQ + d]  = f2b(hh);   // q = h into q_star[:, :512]
        qsh[d] = hh;
    }
    __syncthreads();

    const int s     = offs[b];
    const int e_end = offs[b + 1];

    // ---- phase 1: e[n] = x[n].q (one wave per node) ----
    float q8[8];
#pragma unroll
    for (int j = 0; j < 8; j++) q8[j] = qsh[lane * 8 + j];

    float wmax = -__builtin_inff();
    if (xf32) {
        const float* xp = (const float*)x;
        for (int n = s + w; n < e_end; n += 4) {
            f32x4 v0 = *(const f32x4*)(xp + (size_t)n * DIN + lane * 8);
            f32x4 v1 = *(const f32x4*)(xp + (size_t)n * DIN + lane * 8 + 4);
            float dot = 0.f;
#pragma unroll
            for (int j = 0; j < 4; j++) dot += q8[j] * v0[j];
#pragma unroll
            for (int j = 0; j < 4; j++) dot += q8[4 + j] * v1[j];
#pragma unroll
            for (int off = 32; off > 0; off >>= 1) dot += __shfl_xor(dot, off, 64);
            if (lane == 0) ebuf[n] = dot;
            wmax = fmaxf(wmax, dot);
        }
    } else {
        for (int n = s + w; n < e_end; n += 4) {
            u16x8 xv = *(const u16x8*)(x + (size_t)n * DIN + lane * 8);
            float dot = 0.f;
#pragma unroll
            for (int j = 0; j < 8; j++) dot += q8[j] * b2f(xv[j]);
#pragma unroll
            for (int off = 32; off > 0; off >>= 1) dot += __shfl_xor(dot, off, 64);
            if (lane == 0) ebuf[n] = dot;
            wmax = fmaxf(wmax, dot);
        }
    }
    if (lane == 0) smax[w] = wmax;
    __syncthreads();
    float bmax = fmaxf(fmaxf(smax[0], smax[1]), fmaxf(smax[2], smax[3]));

    // ---- phase 1b: exponentiate + segment sum ----
    float psum = 0.f;
    for (int n = s + tid; n < e_end; n += 256) {
        float ex = __expf(ebuf[n] - bmax);
        ebuf[n] = ex;
        psum += ex;
    }
#pragma unroll
    for (int off = 32; off > 0; off >>= 1) psum += __shfl_xor(psum, off, 64);
    if (lane == 0) ssum[w] = psum;
    __syncthreads();
    float denom = ssum[0] + ssum[1] + ssum[2] + ssum[3];
    float inv = denom > 0.f ? 1.f / denom : 0.f;   // empty graph -> r = 0

    // ---- phase 2: r[d] = inv * sum_n ex[n]*x[n][d] (thread owns 2 dims) ----
    float a0 = 0.f, a1 = 0.f;
    const int d = tid * 2;
    if (xf32) {
        const float* xp = (const float*)x;
        for (int n = s; n < e_end; ++n) {
            float exv = ebuf[n];
            float2 xv = *(const float2*)(xp + (size_t)n * DIN + d);
            a0 += exv * xv.x;
            a1 += exv * xv.y;
        }
    } else {
        for (int n = s; n < e_end; ++n) {
            float exv = ebuf[n];
            unsigned int xv = *(const unsigned int*)(x + (size_t)n * DIN + d);
            a0 += exv * b2f((unsigned short)(xv & 0xffffu));
            a1 += exv * b2f((unsigned short)(xv >> 16));
        }
    }
    A[(size_t)b * KQ + DIN + d]     = f2b(a0 * inv);
    A[(size_t)b * KQ + DIN + d + 1] = f2b(a1 * inv);
}

// ---------------------------------------------------------------------------
// Prep: fused weight W' = Wih (+Whh on k<512) -> bf16; biases -> f32;
// Wpost -> bf16. All reads dtype-dispatched via flags.
// ---------------------------------------------------------------------------
__global__ void prep_weights(const ushort_t* __restrict__ Wih,
                             const ushort_t* __restrict__ Whh,
                             const ushort_t* __restrict__ bih,
                             const ushort_t* __restrict__ bhh,
                             const ushort_t* __restrict__ Wpost,
                             const ushort_t* __restrict__ bpost,
                             ushort_t* __restrict__ Wp,
                             float* __restrict__ biasz,
                             float* __restrict__ biaspost,
                             ushort_t* __restrict__ Wpb,
                             const int* __restrict__ flags)
{
    const int idx = blockIdx.x * 256 + threadIdx.x;
    const int fWih = flags[1], fWhh = flags[2], fbih = flags[3];
    const int fbhh = flags[4], fWpo = flags[5], fbpo = flags[6];

    if (idx < NGATE * KQ) {
        int j = idx >> 10;
        int k = idx & 1023;
        float v = fWih ? ((const float*)Wih)[idx] : b2f(Wih[idx]);
        if (k < DIN) {
            int widx = j * DIN + k;
            v += fWhh ? ((const float*)Whh)[widx] : b2f(Whh[widx]);
        }
        Wp[idx] = f2b(v);
    }
    if (idx < DOUT * KQ) {
        Wpb[idx] = fWpo ? f2b(((const float*)Wpost)[idx]) : Wpost[idx];
    }
    if (idx < NGATE) {
        float v1 = fbih ? ((const float*)bih)[idx] : b2f(bih[idx]);
        float v2 = fbhh ? ((const float*)bhh)[idx] : b2f(bhh[idx]);
        biasz[idx] = v1 + v2;
    }
    if (idx < DOUT) {
        biaspost[idx] = fbpo ? ((const float*)bpost)[idx] : b2f(bpost[idx]);
    }
}

// zero q_star (A) and c — ws is poisoned 0xAA before every launch
__global__ void prep_state(ushort_t* __restrict__ A, float* __restrict__ c)
{
    int idx = blockIdx.x * 256 + threadIdx.x;
    if (idx < BGR * KQ)  A[idx] = 0;
    if (idx < BGR * DIN) c[idx] = 0.f;
}

// CSR offsets from sorted batch; handles int32 or int64 batch.
// int64-as-int32 view shows [low(~mid), high(=0)] at the last two u32 slots,
// so batch[Nn-1] < batch[Nn-2] discriminates exactly (sorted otherwise).
__global__ void prep_offsets(const int* __restrict__ batch, int* __restrict__ offs, int Nn)
{
    int n = blockIdx.x * 256 + threadIdx.x;
    if (n >= Nn) return;
    const bool is64 = batch[Nn - 1] < batch[Nn - 2];
    int cur  = is64 ? batch[2 * n] : batch[n];
    int prev = (n == 0) ? -1 : (is64 ? batch[2 * (n - 1)] : batch[n - 1]);
    for (int bb = prev + 1; bb <= cur; ++bb) offs[bb] = n;
    if (n == Nn - 1) {
        for (int bb = cur + 1; bb <= BGR; ++bb) offs[bb] = Nn;
    }
}

// ---------------------------------------------------------------------------
extern "C" void kernel_launch(void* const* d_in, const int* in_sizes, int n_in,
                              void* d_out, int out_size, void* d_ws, size_t ws_size,
                              hipStream_t stream)
{
    const ushort_t* x     = (const ushort_t*)d_in[0];
    const int*      batch = (const int*)d_in[1];
    const ushort_t* Wih   = (const ushort_t*)d_in[2];
    const ushort_t* Whh   = (const ushort_t*)d_in[3];
    const ushort_t* bih   = (const ushort_t*)d_in[4];
    const ushort_t* bhh   = (const ushort_t*)d_in[5];
    const ushort_t* Wpost = (const ushort_t*)d_in[6];
    const ushort_t* bpost = (const ushort_t*)d_in[7];
    const int Nn = in_sizes[1];

    char* p = (char*)d_ws;
    auto carve = [&](size_t bytes) -> void* {
        char* q = p;
        p += (bytes + 255) & ~(size_t)255;
        return (void*)q;
    };
    ushort_t* Wp       = (ushort_t*)carve((size_t)NGATE * KQ * 2);  // 4 MB
    ushort_t* Wpb      = (ushort_t*)carve((size_t)DOUT * KQ * 2);   // 1 MB
    float*    biasz    = (float*)carve((size_t)NGATE * 4);
    float*    biaspost = (float*)carve((size_t)DOUT * 4);
    float*    z        = (float*)carve((size_t)BGR * NGATE * 4);    // 8 MB
    float*    c        = (float*)carve((size_t)BGR * DIN * 4);      // 2 MB
    ushort_t* A        = (ushort_t*)carve((size_t)BGR * KQ * 2);    // 2 MB
    float*    ebuf     = (float*)carve((size_t)Nn * 4);             // 400 KB
    int*      offs     = (int*)carve((size_t)(BGR + 1) * 4);
    int*      flags    = (int*)carve(16 * 4);

    probe_dtypes<<<1, 256, 0, stream>>>(x, Wih, Whh, bih, bhh, Wpost, bpost, flags);
    prep_weights<<<(NGATE * KQ) / 256, 256, 0, stream>>>(
        Wih, Whh, bih, bhh, Wpost, bpost, Wp, biasz, biaspost, Wpb, flags);
    prep_state<<<(BGR * KQ) / 256, 256, 0, stream>>>(A, c);
    prep_offsets<<<(Nn + 255) / 256, 256, 0, stream>>>(batch, offs, Nn);

    for (int t = 0; t < TSTEPS; ++t) {
        gemm_bt<0><<<dim3(NGATE / BN, BGR / BM), 256, 0, stream>>>(
            A, Wp, biasz, z, BGR, NGATE, KQ);
        attn_step<<<BGR, 256, 0, stream>>>(x, offs, z, c, A, ebuf, flags);
    }
    // Final GEMM: reference output dtype is float32 -> write f32.
    gemm_bt<1><<<dim3(DOUT / BN, BGR / BM), 256, 0, stream>>>(
        A, Wpb, biaspost, (float*)d_out, BGR, DOUT, KQ);
}

// Round 5
// 631.198 us; speedup vs baseline: 1.3451x; 1.3451x over previous
//
#include <hip/hip_runtime.h>
#include <stdint.h>
#include <stddef.h>

#define DIN    512
#define BGR    1024
#define NGATE  2048   // 4*DIN
#define KQ     1024   // 2*DIN (q_star width)
#define DOUT   512
#define TSTEPS 6

typedef unsigned short ushort_t;
typedef short bf16x8 __attribute__((ext_vector_type(8)));
typedef unsigned short u16x8 __attribute__((ext_vector_type(8)));
typedef float f32x4 __attribute__((ext_vector_type(4)));

__device__ __forceinline__ float b2f(unsigned short u) {
    unsigned int i = ((unsigned int)u) << 16;
    float f;
    __builtin_memcpy(&f, &i, 4);
    return f;
}

__device__ __forceinline__ unsigned short f2b(float f) {
    unsigned int i;
    __builtin_memcpy(&i, &f, 4);
    unsigned int lsb = (i >> 16) & 1u;
    i += 0x7fffu + lsb;   // round-to-nearest-even
    return (unsigned short)(i >> 16);
}

__device__ __forceinline__ float fast_sigmoid(float v) {
    return 1.f / (1.f + __expf(-v));
}

__device__ __forceinline__ float fast_tanh(float v) {
    float t = fabsf(v);
    float e = __expf(-2.f * t);
    float r = (1.f - e) / (1.f + e);
    return v < 0.f ? -r : r;
}

// ---------------------------------------------------------------------------
// Dtype probe: flags[t]=1 if tensor t is f32, 0 if bf16 (kept for robustness).
// ---------------------------------------------------------------------------
__global__ void probe_dtypes(const ushort_t* x, const ushort_t* Wih,
                             const ushort_t* Whh, const ushort_t* bih,
                             const ushort_t* bhh, const ushort_t* Wpost,
                             const ushort_t* bpost, int* flags)
{
    __shared__ int cnt[7];
    const int tid = threadIdx.x;
    if (tid < 7) cnt[tid] = 0;
    __syncthreads();
    const int t = tid >> 5;
    const int l = tid & 31;
    if (t < 7) {
        const ushort_t* p = (t == 0) ? x : (t == 1) ? Wih : (t == 2) ? Whh
                          : (t == 3) ? bih : (t == 4) ? bhh
                          : (t == 5) ? Wpost : bpost;
        int good = 0;
        for (int i = 0; i < 4; i++) {
            ushort_t u = p[(l * 4 + i) * 2];
            int ex = (u >> 7) & 0xFF;
            if (ex == 0 || (ex >= 96 && ex <= 143)) good++;
        }
        atomicAdd(&cnt[t], good);
    }
    __syncthreads();
    if (tid < 7) flags[tid] = (cnt[tid] < 96) ? 1 : 0;
}

// ---------------------------------------------------------------------------
// Convert x -> bf16 scratch (8 elements/thread). Handles f32 or bf16 input.
// ---------------------------------------------------------------------------
__global__ void convert_x(const void* __restrict__ xin, ushort_t* __restrict__ xb,
                          long long T, const int* __restrict__ flags)
{
    long long i8 = ((long long)blockIdx.x * 256 + threadIdx.x) * 8;
    if (i8 >= T) return;
    if (flags[0]) {
        const float* xp = (const float*)xin;
        f32x4 v0 = *(const f32x4*)(xp + i8);
        f32x4 v1 = *(const f32x4*)(xp + i8 + 4);
        u16x8 o;
#pragma unroll
        for (int j = 0; j < 4; j++) o[j] = f2b(v0[j]);
#pragma unroll
        for (int j = 0; j < 4; j++) o[4 + j] = f2b(v1[j]);
        *(u16x8*)(xb + i8) = o;
    } else {
        *(u16x8*)(xb + i8) = *(const u16x8*)((const ushort_t*)xin + i8);
    }
}

// ---------------------------------------------------------------------------
// GEMM: C[m][n] = sum_k A[m][k]*B[n][k] (+bias[n]); bf16 inputs, f32 out.
// MODE 0: plain store (z). MODE 1: relu store (final out).
// ---------------------------------------------------------------------------
#define BM 128
#define BN 64
#define BK 32

template <int MODE>
__global__ __launch_bounds__(256)
void gemm_bt(const ushort_t* __restrict__ Ag, const ushort_t* __restrict__ Bg,
             const float* __restrict__ bias, float* __restrict__ Cout,
             int M, int N, int K)
{
    __shared__ __align__(16) ushort_t As[BM * BK];
    __shared__ __align__(16) ushort_t Bs[BN * BK];

    const int tid  = threadIdx.x;
    const int lane = tid & 63;
    const int w    = tid >> 6;
    const int wr   = w >> 1;
    const int wc   = w & 1;
    const int lrow = lane & 15;
    const int quad = lane >> 4;

    const int n0 = blockIdx.x * BN;
    const int m0 = blockIdx.y * BM;

    const int srow = tid >> 2;
    const int scol = (tid & 3) * 8;

    f32x4 acc[4][2];
#pragma unroll
    for (int i = 0; i < 4; i++)
#pragma unroll
        for (int j = 0; j < 2; j++)
            acc[i][j] = (f32x4){0.f, 0.f, 0.f, 0.f};

    for (int kt = 0; kt < K; kt += BK) {
        bf16x8 a0v = *(const bf16x8*)(Ag + ((size_t)(m0 + srow) * K + kt + scol));
        bf16x8 a1v = *(const bf16x8*)(Ag + ((size_t)(m0 + 64 + srow) * K + kt + scol));
        bf16x8 bv  = *(const bf16x8*)(Bg + ((size_t)(n0 + srow) * K + kt + scol));
        __syncthreads();
        *(bf16x8*)&As[srow * BK + scol]        = a0v;
        *(bf16x8*)&As[(64 + srow) * BK + scol] = a1v;
        *(bf16x8*)&Bs[srow * BK + scol]        = bv;
        __syncthreads();

        bf16x8 af[4], bfr[2];
#pragma unroll
        for (int mi = 0; mi < 4; mi++)
            af[mi] = *(const bf16x8*)&As[(wr * 64 + mi * 16 + lrow) * BK + quad * 8];
#pragma unroll
        for (int ni = 0; ni < 2; ni++)
            bfr[ni] = *(const bf16x8*)&Bs[(wc * 32 + ni * 16 + lrow) * BK + quad * 8];

#pragma unroll
        for (int mi = 0; mi < 4; mi++)
#pragma unroll
            for (int ni = 0; ni < 2; ni++)
                acc[mi][ni] = __builtin_amdgcn_mfma_f32_16x16x32_bf16(
                    af[mi], bfr[ni], acc[mi][ni], 0, 0, 0);
    }

#pragma unroll
    for (int mi = 0; mi < 4; mi++) {
#pragma unroll
        for (int ni = 0; ni < 2; ni++) {
#pragma unroll
            for (int r = 0; r < 4; r++) {
                int gm = m0 + wr * 64 + mi * 16 + quad * 4 + r;
                int gn = n0 + wc * 32 + ni * 16 + lrow;
                float v = acc[mi][ni][r] + bias[gn];
                if (MODE == 1) {
                    if (!(v > 0.f) && (v == v)) v = 0.f;
                }
                Cout[(size_t)gm * N + gn] = v;
            }
        }
    }
}

// ---------------------------------------------------------------------------
// Fused LSTM cell + ONE-PASS online-softmax attention (flash-style).
// One block (4 waves) per graph. Each wave streams disjoint nodes (stride 4),
// keeps (m, l, acc[8]) in registers; waves merge via LDS at the end.
// XMODE 0: x is bf16 (converted scratch). XMODE 1: x is f32 (direct).
// ---------------------------------------------------------------------------
template <int XMODE>
__global__ __launch_bounds__(256)
void attn_step2(const void* __restrict__ xptr, const int* __restrict__ offs,
                const float* __restrict__ z, float* __restrict__ c,
                ushort_t* __restrict__ A)
{
    const int b    = blockIdx.x;
    const int tid  = threadIdx.x;
    const int lane = tid & 63;
    const int w    = tid >> 6;

    __shared__ float qsh[DIN];
    __shared__ float accL[4][DIN];   // 8 KB
    __shared__ float mw[4], lw[4];

    // ---- phase 0: LSTM cell (gate order i,f,g,o) ----
    const float* zrow = z + (size_t)b * NGATE;
    for (int d = tid; d < DIN; d += 256) {
        float zi = zrow[d];
        float zf = zrow[DIN + d];
        float zg = zrow[2 * DIN + d];
        float zo = zrow[3 * DIN + d];
        float cc = c[(size_t)b * DIN + d];
        cc = fast_sigmoid(zf) * cc + fast_sigmoid(zi) * fast_tanh(zg);
        float hh = fast_sigmoid(zo) * fast_tanh(cc);
        c[(size_t)b * DIN + d] = cc;
        A[(size_t)b * KQ + d]  = f2b(hh);   // q = h into q_star[:, :512]
        qsh[d] = hh;
    }
    __syncthreads();

    const int s  = offs[b];
    const int en = offs[b + 1];

    float q8[8];
#pragma unroll
    for (int j = 0; j < 8; j++) q8[j] = qsh[lane * 8 + j];

    const float NEG_INF = -__builtin_inff();
    float m = NEG_INF, l = 0.f;
    float acc[8];
#pragma unroll
    for (int j = 0; j < 8; j++) acc[j] = 0.f;

    // row loader: lane covers dims [lane*8, lane*8+8)
    auto load_row = [&](int n, float* xf) {
        if (XMODE == 0) {
            u16x8 xv = *(const u16x8*)((const ushort_t*)xptr + (size_t)n * DIN + lane * 8);
#pragma unroll
            for (int j = 0; j < 8; j++) xf[j] = b2f(xv[j]);
        } else {
            const float* xp = (const float*)xptr;
            f32x4 v0 = *(const f32x4*)(xp + (size_t)n * DIN + lane * 8);
            f32x4 v1 = *(const f32x4*)(xp + (size_t)n * DIN + lane * 8 + 4);
#pragma unroll
            for (int j = 0; j < 4; j++) { xf[j] = v0[j]; xf[4 + j] = v1[j]; }
        }
    };

    // ---- one pass over this wave's nodes with next-row prefetch ----
    float xf[8];
    int n = s + w;
    if (n < en) load_row(n, xf);
    for (; n < en; n += 4) {
        float xn[8];
        const int nn = n + 4;
        if (nn < en) load_row(nn, xn);

        float e = 0.f;
#pragma unroll
        for (int j = 0; j < 8; j++) e += q8[j] * xf[j];
#pragma unroll
        for (int off = 32; off > 0; off >>= 1) e += __shfl_xor(e, off, 64);

        float mn_   = fmaxf(m, e);
        float alpha = __expf(m - mn_);     // first node: exp(-inf)=0
        float pp    = __expf(e - mn_);
        l = l * alpha + pp;
#pragma unroll
        for (int j = 0; j < 8; j++) acc[j] = acc[j] * alpha + pp * xf[j];
        m = mn_;

#pragma unroll
        for (int j = 0; j < 8; j++) xf[j] = xn[j];
    }

    // ---- merge 4 waves (flash combine) ----
    if (lane == 0) { mw[w] = m; lw[w] = l; }
#pragma unroll
    for (int j = 0; j < 8; j++) accL[w][lane * 8 + j] = acc[j];
    __syncthreads();

    const float M = fmaxf(fmaxf(mw[0], mw[1]), fmaxf(mw[2], mw[3]));
    const int d0 = tid * 2;
    float r0 = 0.f, r1 = 0.f, lt = 0.f;
#pragma unroll
    for (int ww = 0; ww < 4; ww++) {
        float mwv = mw[ww];
        float a = (mwv == NEG_INF) ? 0.f : __expf(mwv - M);
        lt += a * lw[ww];
        r0 += a * accL[ww][d0];
        r1 += a * accL[ww][d0 + 1];
    }
    float inv = lt > 0.f ? 1.f / lt : 0.f;   // empty graph -> r = 0
    A[(size_t)b * KQ + DIN + d0]     = f2b(r0 * inv);
    A[(size_t)b * KQ + DIN + d0 + 1] = f2b(r1 * inv);
}

// ---------------------------------------------------------------------------
// Prep: fused weight W' = Wih (+Whh on k<512) -> bf16; biases -> f32;
// Wpost -> bf16. All reads dtype-dispatched via flags.
// ---------------------------------------------------------------------------
__global__ void prep_weights(const ushort_t* __restrict__ Wih,
                             const ushort_t* __restrict__ Whh,
                             const ushort_t* __restrict__ bih,
                             const ushort_t* __restrict__ bhh,
                             const ushort_t* __restrict__ Wpost,
                             const ushort_t* __restrict__ bpost,
                             ushort_t* __restrict__ Wp,
                             float* __restrict__ biasz,
                             float* __restrict__ biaspost,
                             ushort_t* __restrict__ Wpb,
                             const int* __restrict__ flags)
{
    const int idx = blockIdx.x * 256 + threadIdx.x;
    const int fWih = flags[1], fWhh = flags[2], fbih = flags[3];
    const int fbhh = flags[4], fWpo = flags[5], fbpo = flags[6];

    if (idx < NGATE * KQ) {
        int j = idx >> 10;
        int k = idx & 1023;
        float v = fWih ? ((const float*)Wih)[idx] : b2f(Wih[idx]);
        if (k < DIN) {
            int widx = j * DIN + k;
            v += fWhh ? ((const float*)Whh)[widx] : b2f(Whh[widx]);
        }
        Wp[idx] = f2b(v);
    }
    if (idx < DOUT * KQ) {
        Wpb[idx] = fWpo ? f2b(((const float*)Wpost)[idx]) : Wpost[idx];
    }
    if (idx < NGATE) {
        float v1 = fbih ? ((const float*)bih)[idx] : b2f(bih[idx]);
        float v2 = fbhh ? ((const float*)bhh)[idx] : b2f(bhh[idx]);
        biasz[idx] = v1 + v2;
    }
    if (idx < DOUT) {
        biaspost[idx] = fbpo ? ((const float*)bpost)[idx] : b2f(bpost[idx]);
    }
}

// zero q_star (A) and c — ws is poisoned 0xAA before every launch
__global__ void prep_state(ushort_t* __restrict__ A, float* __restrict__ c)
{
    int idx = blockIdx.x * 256 + threadIdx.x;
    if (idx < BGR * KQ)  A[idx] = 0;
    if (idx < BGR * DIN) c[idx] = 0.f;
}

// CSR offsets from sorted batch; handles int32 or int64 batch.
__global__ void prep_offsets(const int* __restrict__ batch, int* __restrict__ offs, int Nn)
{
    int n = blockIdx.x * 256 + threadIdx.x;
    if (n >= Nn) return;
    const bool is64 = batch[Nn - 1] < batch[Nn - 2];
    int cur  = is64 ? batch[2 * n] : batch[n];
    int prev = (n == 0) ? -1 : (is64 ? batch[2 * (n - 1)] : batch[n - 1]);
    for (int bb = prev + 1; bb <= cur; ++bb) offs[bb] = n;
    if (n == Nn - 1) {
        for (int bb = cur + 1; bb <= BGR; ++bb) offs[bb] = Nn;
    }
}

// ---------------------------------------------------------------------------
extern "C" void kernel_launch(void* const* d_in, const int* in_sizes, int n_in,
                              void* d_out, int out_size, void* d_ws, size_t ws_size,
                              hipStream_t stream)
{
    const ushort_t* x     = (const ushort_t*)d_in[0];
    const int*      batch = (const int*)d_in[1];
    const ushort_t* Wih   = (const ushort_t*)d_in[2];
    const ushort_t* Whh   = (const ushort_t*)d_in[3];
    const ushort_t* bih   = (const ushort_t*)d_in[4];
    const ushort_t* bhh   = (const ushort_t*)d_in[5];
    const ushort_t* Wpost = (const ushort_t*)d_in[6];
    const ushort_t* bpost = (const ushort_t*)d_in[7];
    const int Nn = in_sizes[1];
    const long long Tx = (long long)in_sizes[0];   // Nn * DIN elements

    char* p = (char*)d_ws;
    auto carve = [&](size_t bytes) -> void* {
        char* q = p;
        p += (bytes + 255) & ~(size_t)255;
        return (void*)q;
    };
    ushort_t* Wp       = (ushort_t*)carve((size_t)NGATE * KQ * 2);  // 4 MB
    ushort_t* Wpb      = (ushort_t*)carve((size_t)DOUT * KQ * 2);   // 1 MB
    float*    biasz    = (float*)carve((size_t)NGATE * 4);
    float*    biaspost = (float*)carve((size_t)DOUT * 4);
    float*    z        = (float*)carve((size_t)BGR * NGATE * 4);    // 8 MB
    float*    c        = (float*)carve((size_t)BGR * DIN * 4);      // 2 MB
    ushort_t* A        = (ushort_t*)carve((size_t)BGR * KQ * 2);    // 2 MB
    int*      offs     = (int*)carve((size_t)(BGR + 1) * 4);
    int*      flags    = (int*)carve(16 * 4);
    // bf16 copy of x (large) — last carve, with fallback if ws too small
    size_t used = (size_t)(p - (char*)d_ws);
    const bool use_xb = (ws_size >= used + (size_t)Tx * 2 + 256);
    ushort_t* xb = use_xb ? (ushort_t*)carve((size_t)Tx * 2) : nullptr;

    probe_dtypes<<<1, 256, 0, stream>>>(x, Wih, Whh, bih, bhh, Wpost, bpost, flags);
    prep_weights<<<(NGATE * KQ) / 256, 256, 0, stream>>>(
        Wih, Whh, bih, bhh, Wpost, bpost, Wp, biasz, biaspost, Wpb, flags);
    prep_state<<<(BGR * KQ) / 256, 256, 0, stream>>>(A, c);
    prep_offsets<<<(Nn + 255) / 256, 256, 0, stream>>>(batch, offs, Nn);
    if (use_xb) {
        int cblocks = (int)((Tx / 8 + 255) / 256);
        convert_x<<<cblocks, 256, 0, stream>>>(x, xb, Tx, flags);
    }

    for (int t = 0; t < TSTEPS; ++t) {
        gemm_bt<0><<<dim3(NGATE / BN, BGR / BM), 256, 0, stream>>>(
            A, Wp, biasz, z, BGR, NGATE, KQ);
        if (use_xb)
            attn_step2<0><<<BGR, 256, 0, stream>>>(xb, offs, z, c, A);
        else
            attn_step2<1><<<BGR, 256, 0, stream>>>(x, offs, z, c, A);
    }
    gemm_bt<1><<<dim3(DOUT / BN, BGR / BM), 256, 0, stream>>>(
        A, Wpb, biaspost, (float*)d_out, BGR, DOUT, KQ);
}

// Round 6
// 571.217 us; speedup vs baseline: 1.4864x; 1.1050x over previous
//
#include <hip/hip_runtime.h>
#include <stdint.h>
#include <stddef.h>

#define DIN    512
#define BGR    1024
#define NGATE  2048   // 4*DIN
#define KQ     1024   // 2*DIN (q_star width)
#define DOUT   512
#define TSTEPS 6

typedef unsigned short ushort_t;
typedef short bf16x8 __attribute__((ext_vector_type(8)));
typedef unsigned short u16x8 __attribute__((ext_vector_type(8)));
typedef float f32x4 __attribute__((ext_vector_type(4)));

__device__ __forceinline__ float b2f(unsigned short u) {
    unsigned int i = ((unsigned int)u) << 16;
    float f;
    __builtin_memcpy(&f, &i, 4);
    return f;
}

__device__ __forceinline__ unsigned short f2b(float f) {
    unsigned int i;
    __builtin_memcpy(&i, &f, 4);
    unsigned int lsb = (i >> 16) & 1u;
    i += 0x7fffu + lsb;   // round-to-nearest-even
    return (unsigned short)(i >> 16);
}

__device__ __forceinline__ float fast_sigmoid(float v) {
    return 1.f / (1.f + __expf(-v));
}

__device__ __forceinline__ float fast_tanh(float v) {
    float t = fabsf(v);
    float e = __expf(-2.f * t);
    float r = (1.f - e) / (1.f + e);
    return v < 0.f ? -r : r;
}

// ---------------------------------------------------------------------------
// Dtype probe: flags[t]=1 if tensor t is f32, 0 if bf16.
// ---------------------------------------------------------------------------
__global__ void probe_dtypes(const ushort_t* x, const ushort_t* Wih,
                             const ushort_t* Whh, const ushort_t* bih,
                             const ushort_t* bhh, const ushort_t* Wpost,
                             const ushort_t* bpost, int* flags)
{
    __shared__ int cnt[7];
    const int tid = threadIdx.x;
    if (tid < 7) cnt[tid] = 0;
    __syncthreads();
    const int t = tid >> 5;
    const int l = tid & 31;
    if (t < 7) {
        const ushort_t* p = (t == 0) ? x : (t == 1) ? Wih : (t == 2) ? Whh
                          : (t == 3) ? bih : (t == 4) ? bhh
                          : (t == 5) ? Wpost : bpost;
        int good = 0;
        for (int i = 0; i < 4; i++) {
            ushort_t u = p[(l * 4 + i) * 2];
            int ex = (u >> 7) & 0xFF;
            if (ex == 0 || (ex >= 96 && ex <= 143)) good++;
        }
        atomicAdd(&cnt[t], good);
    }
    __syncthreads();
    if (tid < 7) flags[tid] = (cnt[tid] < 96) ? 1 : 0;
}

// ---------------------------------------------------------------------------
// GEMM 64x64 tile: C[m][n] = sum_k A[m][k]*B[n][k] (+bias[n]); bf16 in, f32 out.
// MODE 0: plain store (z). MODE 1: relu store (final out).
// 256 threads = 4 waves in 2x2; each wave computes 32x32 (2x2 MFMA tiles).
// 2 blocks/CU for the z shape (512 blocks) -> cross-block latency overlap.
// ---------------------------------------------------------------------------
#define BM 64
#define BN 64
#define BK 32

template <int MODE>
__global__ __launch_bounds__(256)
void gemm_bt(const ushort_t* __restrict__ Ag, const ushort_t* __restrict__ Bg,
             const float* __restrict__ bias, float* __restrict__ Cout,
             int M, int N, int K)
{
    __shared__ __align__(16) ushort_t As[BM * BK];
    __shared__ __align__(16) ushort_t Bs[BN * BK];

    const int tid  = threadIdx.x;
    const int lane = tid & 63;
    const int w    = tid >> 6;
    const int wr   = w >> 1;
    const int wc   = w & 1;
    const int lrow = lane & 15;
    const int quad = lane >> 4;

    const int n0 = blockIdx.x * BN;
    const int m0 = blockIdx.y * BM;

    const int srow = tid >> 2;        // 0..63
    const int scol = (tid & 3) * 8;   // 0,8,16,24

    f32x4 acc[2][2];
#pragma unroll
    for (int i = 0; i < 2; i++)
#pragma unroll
        for (int j = 0; j < 2; j++)
            acc[i][j] = (f32x4){0.f, 0.f, 0.f, 0.f};

    for (int kt = 0; kt < K; kt += BK) {
        bf16x8 av = *(const bf16x8*)(Ag + ((size_t)(m0 + srow) * K + kt + scol));
        bf16x8 bv = *(const bf16x8*)(Bg + ((size_t)(n0 + srow) * K + kt + scol));
        __syncthreads();
        *(bf16x8*)&As[srow * BK + scol] = av;
        *(bf16x8*)&Bs[srow * BK + scol] = bv;
        __syncthreads();

        bf16x8 af[2], bfr[2];
#pragma unroll
        for (int mi = 0; mi < 2; mi++)
            af[mi] = *(const bf16x8*)&As[(wr * 32 + mi * 16 + lrow) * BK + quad * 8];
#pragma unroll
        for (int ni = 0; ni < 2; ni++)
            bfr[ni] = *(const bf16x8*)&Bs[(wc * 32 + ni * 16 + lrow) * BK + quad * 8];

#pragma unroll
        for (int mi = 0; mi < 2; mi++)
#pragma unroll
            for (int ni = 0; ni < 2; ni++)
                acc[mi][ni] = __builtin_amdgcn_mfma_f32_16x16x32_bf16(
                    af[mi], bfr[ni], acc[mi][ni], 0, 0, 0);
    }

    // D layout: row = quad*4 + reg, col = lane&15   [m89/m91]
#pragma unroll
    for (int mi = 0; mi < 2; mi++) {
#pragma unroll
        for (int ni = 0; ni < 2; ni++) {
#pragma unroll
            for (int r = 0; r < 4; r++) {
                int gm = m0 + wr * 32 + mi * 16 + quad * 4 + r;
                int gn = n0 + wc * 32 + ni * 16 + lrow;
                float v = acc[mi][ni][r] + bias[gn];
                if (MODE == 1) {
                    if (!(v > 0.f) && (v == v)) v = 0.f;   // NaN-transparent relu
                }
                Cout[(size_t)gm * N + gn] = v;
            }
        }
    }
}

// ---------------------------------------------------------------------------
// Fused LSTM cell + one-pass online-softmax attention, 2-row interleaved.
// One block (4 waves) per graph; wave handles rows s+w, s+w+4, ... in pairs
// (n, n+4) with next-pair prefetch (4 loads in flight, ILP-2 shuffle chains).
// XMODE 0: read bf16 from xb.
// XMODE 1: step 0 — runtime branch on flags[0], read x (f32|bf16), WRITE xb.
// XMODE 2: fallback — runtime branch read from x, no xb write.
// ---------------------------------------------------------------------------
template <int XMODE>
__global__ __launch_bounds__(256)
void attn_step(const ushort_t* __restrict__ xbsrc, const ushort_t* __restrict__ xraw,
               ushort_t* __restrict__ xbdst, const int* __restrict__ offs,
               const float* __restrict__ z, float* __restrict__ c,
               ushort_t* __restrict__ A, const int* __restrict__ flags)
{
    const int b    = blockIdx.x;
    const int tid  = threadIdx.x;
    const int lane = tid & 63;
    const int w    = tid >> 6;
    const int xf   = (XMODE == 0) ? 0 : flags[0];   // uniform

    __shared__ float qsh[DIN];
    __shared__ float accL[4][DIN];   // 8 KB
    __shared__ float mw[4], lw[4];

    // ---- phase 0: LSTM cell (gate order i,f,g,o) ----
    const float* zrow = z + (size_t)b * NGATE;
    for (int d = tid; d < DIN; d += 256) {
        float zi = zrow[d];
        float zf = zrow[DIN + d];
        float zg = zrow[2 * DIN + d];
        float zo = zrow[3 * DIN + d];
        float cc = c[(size_t)b * DIN + d];
        cc = fast_sigmoid(zf) * cc + fast_sigmoid(zi) * fast_tanh(zg);
        float hh = fast_sigmoid(zo) * fast_tanh(cc);
        c[(size_t)b * DIN + d] = cc;
        A[(size_t)b * KQ + d]  = f2b(hh);   // q = h into q_star[:, :512]
        qsh[d] = hh;
    }
    __syncthreads();

    const int s  = offs[b];
    const int en = offs[b + 1];

    float q8[8];
#pragma unroll
    for (int j = 0; j < 8; j++) q8[j] = qsh[lane * 8 + j];

    const float NEG_INF = -__builtin_inff();
    float m = NEG_INF, l = 0.f;
    float acc[8];
#pragma unroll
    for (int j = 0; j < 8; j++) acc[j] = 0.f;

    // lane covers dims [lane*8, lane*8+8)
    auto load_row = [&](int n, float* v) {
        if (XMODE == 0 || !xf) {
            const ushort_t* src = (XMODE == 0) ? xbsrc : xraw;
            u16x8 xv = *(const u16x8*)(src + (size_t)n * DIN + lane * 8);
#pragma unroll
            for (int j = 0; j < 8; j++) v[j] = b2f(xv[j]);
            if (XMODE == 1)
                *(u16x8*)(xbdst + (size_t)n * DIN + lane * 8) = xv;
        } else {
            const float* xp = (const float*)xraw;
            f32x4 v0 = *(const f32x4*)(xp + (size_t)n * DIN + lane * 8);
            f32x4 v1 = *(const f32x4*)(xp + (size_t)n * DIN + lane * 8 + 4);
#pragma unroll
            for (int j = 0; j < 4; j++) { v[j] = v0[j]; v[4 + j] = v1[j]; }
            if (XMODE == 1) {
                u16x8 o;
#pragma unroll
                for (int j = 0; j < 8; j++) o[j] = f2b(v[j]);
                *(u16x8*)(xbdst + (size_t)n * DIN + lane * 8) = o;
            }
        }
    };

    auto update = [&](float e, const float* xv) {
        float mn = fmaxf(m, e);
        float al = __expf(m - mn);    // first node: exp(-inf)=0
        float pp = __expf(e - mn);
        l = l * al + pp;
#pragma unroll
        for (int j = 0; j < 8; j++) acc[j] = acc[j] * al + pp * xv[j];
        m = mn;
    };

    // ---- pair-pipelined pass (rows n, n+4; prefetch n+8, n+12) ----
    float xa[8] = {0.f}, xc[8] = {0.f};
    int n = s + w;
    if (n < en)     load_row(n, xa);
    if (n + 4 < en) load_row(n + 4, xc);
    for (; n < en; n += 8) {
        float pa[8], pc[8];
        const int np = n + 8;
        if (np < en)     load_row(np, pa);
        if (np + 4 < en) load_row(np + 4, pc);

        float e1 = 0.f, e2 = 0.f;
#pragma unroll
        for (int j = 0; j < 8; j++) { e1 += q8[j] * xa[j]; e2 += q8[j] * xc[j]; }
#pragma unroll
        for (int off = 32; off > 0; off >>= 1) {
            e1 += __shfl_xor(e1, off, 64);
            e2 += __shfl_xor(e2, off, 64);
        }

        update(e1, xa);
        if (n + 4 < en) update(e2, xc);

#pragma unroll
        for (int j = 0; j < 8; j++) { xa[j] = pa[j]; xc[j] = pc[j]; }
    }

    // ---- merge 4 waves (flash combine) ----
    if (lane == 0) { mw[w] = m; lw[w] = l; }
#pragma unroll
    for (int j = 0; j < 8; j++) accL[w][lane * 8 + j] = acc[j];
    __syncthreads();

    const float M = fmaxf(fmaxf(mw[0], mw[1]), fmaxf(mw[2], mw[3]));
    const int d0 = tid * 2;
    float r0 = 0.f, r1 = 0.f, lt = 0.f;
#pragma unroll
    for (int ww = 0; ww < 4; ww++) {
        float mwv = mw[ww];
        float a = (mwv == NEG_INF) ? 0.f : __expf(mwv - M);
        lt += a * lw[ww];
        r0 += a * accL[ww][d0];
        r1 += a * accL[ww][d0 + 1];
    }
    float inv = lt > 0.f ? 1.f / lt : 0.f;   // empty graph -> r = 0
    A[(size_t)b * KQ + DIN + d0]     = f2b(r0 * inv);
    A[(size_t)b * KQ + DIN + d0 + 1] = f2b(r1 * inv);
}

// ---------------------------------------------------------------------------
// Prep: fused weight W' = Wih (+Whh on k<512) -> bf16; biases -> f32;
// Wpost -> bf16. All reads dtype-dispatched via flags.
// ---------------------------------------------------------------------------
__global__ void prep_weights(const ushort_t* __restrict__ Wih,
                             const ushort_t* __restrict__ Whh,
                             const ushort_t* __restrict__ bih,
                             const ushort_t* __restrict__ bhh,
                             const ushort_t* __restrict__ Wpost,
                             const ushort_t* __restrict__ bpost,
                             ushort_t* __restrict__ Wp,
                             float* __restrict__ biasz,
                             float* __restrict__ biaspost,
                             ushort_t* __restrict__ Wpb,
                             const int* __restrict__ flags)
{
    const int idx = blockIdx.x * 256 + threadIdx.x;
    const int fWih = flags[1], fWhh = flags[2], fbih = flags[3];
    const int fbhh = flags[4], fWpo = flags[5], fbpo = flags[6];

    if (idx < NGATE * KQ) {
        int j = idx >> 10;
        int k = idx & 1023;
        float v = fWih ? ((const float*)Wih)[idx] : b2f(Wih[idx]);
        if (k < DIN) {
            int widx = j * DIN + k;
            v += fWhh ? ((const float*)Whh)[widx] : b2f(Whh[widx]);
        }
        Wp[idx] = f2b(v);
    }
    if (idx < DOUT * KQ) {
        Wpb[idx] = fWpo ? f2b(((const float*)Wpost)[idx]) : Wpost[idx];
    }
    if (idx < NGATE) {
        float v1 = fbih ? ((const float*)bih)[idx] : b2f(bih[idx]);
        float v2 = fbhh ? ((const float*)bhh)[idx] : b2f(bhh[idx]);
        biasz[idx] = v1 + v2;
    }
    if (idx < DOUT) {
        biaspost[idx] = fbpo ? ((const float*)bpost)[idx] : b2f(bpost[idx]);
    }
}

// zero q_star (A) and c — ws is poisoned 0xAA before every launch
__global__ void prep_state(ushort_t* __restrict__ A, float* __restrict__ c)
{
    int idx = blockIdx.x * 256 + threadIdx.x;
    if (idx < BGR * KQ)  A[idx] = 0;
    if (idx < BGR * DIN) c[idx] = 0.f;
}

// CSR offsets from sorted batch; handles int32 or int64 batch.
__global__ void prep_offsets(const int* __restrict__ batch, int* __restrict__ offs, int Nn)
{
    int n = blockIdx.x * 256 + threadIdx.x;
    if (n >= Nn) return;
    const bool is64 = batch[Nn - 1] < batch[Nn - 2];
    int cur  = is64 ? batch[2 * n] : batch[n];
    int prev = (n == 0) ? -1 : (is64 ? batch[2 * (n - 1)] : batch[n - 1]);
    for (int bb = prev + 1; bb <= cur; ++bb) offs[bb] = n;
    if (n == Nn - 1) {
        for (int bb = cur + 1; bb <= BGR; ++bb) offs[bb] = Nn;
    }
}

// ---------------------------------------------------------------------------
extern "C" void kernel_launch(void* const* d_in, const int* in_sizes, int n_in,
                              void* d_out, int out_size, void* d_ws, size_t ws_size,
                              hipStream_t stream)
{
    const ushort_t* x     = (const ushort_t*)d_in[0];
    const int*      batch = (const int*)d_in[1];
    const ushort_t* Wih   = (const ushort_t*)d_in[2];
    const ushort_t* Whh   = (const ushort_t*)d_in[3];
    const ushort_t* bih   = (const ushort_t*)d_in[4];
    const ushort_t* bhh   = (const ushort_t*)d_in[5];
    const ushort_t* Wpost = (const ushort_t*)d_in[6];
    const ushort_t* bpost = (const ushort_t*)d_in[7];
    const int Nn = in_sizes[1];
    const long long Tx = (long long)in_sizes[0];   // Nn * DIN elements

    char* p = (char*)d_ws;
    auto carve = [&](size_t bytes) -> void* {
        char* q = p;
        p += (bytes + 255) & ~(size_t)255;
        return (void*)q;
    };
    ushort_t* Wp       = (ushort_t*)carve((size_t)NGATE * KQ * 2);  // 4 MB
    ushort_t* Wpb      = (ushort_t*)carve((size_t)DOUT * KQ * 2);   // 1 MB
    float*    biasz    = (float*)carve((size_t)NGATE * 4);
    float*    biaspost = (float*)carve((size_t)DOUT * 4);
    float*    z        = (float*)carve((size_t)BGR * NGATE * 4);    // 8 MB
    float*    c        = (float*)carve((size_t)BGR * DIN * 4);      // 2 MB
    ushort_t* A        = (ushort_t*)carve((size_t)BGR * KQ * 2);    // 2 MB
    int*      offs     = (int*)carve((size_t)(BGR + 1) * 4);
    int*      flags    = (int*)carve(16 * 4);
    size_t used = (size_t)(p - (char*)d_ws);
    const bool use_xb = (ws_size >= used + (size_t)Tx * 2 + 256);
    ushort_t* xb = use_xb ? (ushort_t*)carve((size_t)Tx * 2) : nullptr;

    probe_dtypes<<<1, 256, 0, stream>>>(x, Wih, Whh, bih, bhh, Wpost, bpost, flags);
    prep_weights<<<(NGATE * KQ) / 256, 256, 0, stream>>>(
        Wih, Whh, bih, bhh, Wpost, bpost, Wp, biasz, biaspost, Wpb, flags);
    prep_state<<<(BGR * KQ) / 256, 256, 0, stream>>>(A, c);
    prep_offsets<<<(Nn + 255) / 256, 256, 0, stream>>>(batch, offs, Nn);

    for (int t = 0; t < TSTEPS; ++t) {
        gemm_bt<0><<<dim3(NGATE / BN, BGR / BM), 256, 0, stream>>>(
            A, Wp, biasz, z, BGR, NGATE, KQ);
        if (use_xb) {
            if (t == 0)
                attn_step<1><<<BGR, 256, 0, stream>>>(xb, x, xb, offs, z, c, A, flags);
            else
                attn_step<0><<<BGR, 256, 0, stream>>>(xb, x, xb, offs, z, c, A, flags);
        } else {
            attn_step<2><<<BGR, 256, 0, stream>>>(x, x, nullptr, offs, z, c, A, flags);
        }
    }
    gemm_bt<1><<<dim3(DOUT / BN, BGR / BM), 256, 0, stream>>>(
        A, Wpb, biaspost, (float*)d_out, BGR, DOUT, KQ);
}